// Round 5
// baseline (544.936 us; speedup 1.0000x reference)
//
#include <hip/hip_runtime.h>
#include <stdint.h>

typedef unsigned short u16;
typedef __bf16 bf16;
typedef bf16 bf16x8 __attribute__((ext_vector_type(8)));
typedef u16 u16x8 __attribute__((ext_vector_type(8)));
typedef float f32x4 __attribute__((ext_vector_type(4)));

__device__ __forceinline__ u16 f2bf(float f) {
  union { float f; unsigned u; } v; v.f = f;
  unsigned u = v.u;
  u += 0x7FFFu + ((u >> 16) & 1u);   // RNE
  return (u16)(u >> 16);
}

__device__ __forceinline__ bf16x8 as_bf16x8(u16x8 v) {
  return __builtin_bit_cast(bf16x8, v);
}

__device__ __forceinline__ f32x4 mfma16(bf16x8 a, bf16x8 b, f32x4 c) {
  return __builtin_amdgcn_mfma_f32_16x16x32_bf16(a, b, c, 0, 0, 0);
}

// ---------------------------------------------------------------------------
// w22 transpose + cvt: src [R][256] f32 -> dst[o][r] bf16  (16B stores)
// ---------------------------------------------------------------------------
__global__ __launch_bounds__(256) void k_transpose(const float* __restrict__ src,
    u16* __restrict__ dst, long dstStride, long dstOff) {
  __shared__ float tile[64][65];
  const int t = threadIdx.x;
  const int tr = t >> 6, tc = t & 63;
  const long rb = (long)blockIdx.x * 64;
  const int ob = blockIdx.y * 64;
#pragma unroll
  for (int i = 0; i < 16; ++i) {
    int r = i * 4 + tr;
    tile[r][tc] = src[(rb + r) * 256 + ob + tc];
  }
  __syncthreads();
  const int orow = t >> 2, seg = t & 3;
#pragma unroll
  for (int h = 0; h < 2; ++h) {
    u16x8 v;
#pragma unroll
    for (int j = 0; j < 8; ++j) v[j] = f2bf(tile[seg * 16 + h * 8 + j][orow]);
    *(u16x8*)&dst[(long)(ob + orow) * dstStride + dstOff + rb + seg * 16 + h * 8] = v;
  }
}

// ---------------------------------------------------------------------------
// 5 small transposes merged: grid (28, 4)
// ---------------------------------------------------------------------------
__global__ __launch_bounds__(256) void k_transpose_multi(
    const float* __restrict__ b22, const float* __restrict__ w11,
    const float* __restrict__ w21, const float* __restrict__ w12,
    const float* __restrict__ w3, u16* __restrict__ W2T, u16* __restrict__ W11T,
    u16* __restrict__ W21T, u16* __restrict__ W12T, u16* __restrict__ W3T) {
  __shared__ float tile[64][65];
  const int x = blockIdx.x;
  const float* src; u16* dst; long stride, off; int rb;
  if (x < 4)       { src = b22; dst = W2T;  stride = 65792; off = 65536; rb = x; }
  else if (x < 12) { src = w11; dst = W11T; stride = 512;   off = 0;     rb = x - 4; }
  else if (x < 20) { src = w21; dst = W21T; stride = 512;   off = 0;     rb = x - 12; }
  else if (x < 24) { src = w12; dst = W12T; stride = 256;   off = 0;     rb = x - 20; }
  else             { src = w3;  dst = W3T;  stride = 256;   off = 0;     rb = x - 24; }
  const long rbase = (long)rb * 64;
  const int t = threadIdx.x;
  const int tr = t >> 6, tc = t & 63;
  const int ob = blockIdx.y * 64;
#pragma unroll
  for (int i = 0; i < 16; ++i) {
    int r = i * 4 + tr;
    tile[r][tc] = src[(rbase + r) * 256 + ob + tc];
  }
  __syncthreads();
  const int orow = t >> 2, seg = t & 3;
#pragma unroll
  for (int h = 0; h < 2; ++h) {
    u16x8 v;
#pragma unroll
    for (int j = 0; j < 8; ++j) v[j] = f2bf(tile[seg * 16 + h * 8 + j][orow]);
    *(u16x8*)&dst[(long)(ob + orow) * stride + off + rbase + seg * 16 + h * 8] = v;
  }
}

// ---------------------------------------------------------------------------
// Small MFMA GEMM: h = relu(cat @ W^T + bias), f32 out. grid (256, 2).
// ---------------------------------------------------------------------------
__device__ __forceinline__ void gemm_small_core(const float* A0, const float* A1,
    int K, const u16* WT, f32x4 (&acc)[4], int o0, long row) {
  const int lane = threadIdx.x & 63;
  const int l15 = lane & 15, lhi = lane >> 4;
  const int kg = lhi * 8;
  for (int ks = 0; ks < K; ks += 32) {
    int k = ks + kg;
    const float* ap = (A1 != nullptr && k >= 256) ? (A1 + row * 256 + (k - 256))
                                                  : (A0 + row * 256 + k);
    f32x4 f0 = *(const f32x4*)ap;
    f32x4 f1 = *(const f32x4*)(ap + 4);
    u16x8 a;
    a[0]=f2bf(f0[0]); a[1]=f2bf(f0[1]); a[2]=f2bf(f0[2]); a[3]=f2bf(f0[3]);
    a[4]=f2bf(f1[0]); a[5]=f2bf(f1[1]); a[6]=f2bf(f1[2]); a[7]=f2bf(f1[3]);
    bf16x8 av = as_bf16x8(a);
#pragma unroll
    for (int nf = 0; nf < 4; ++nf) {
      int o = o0 + nf * 16 + l15;
      u16x8 braw = *(const u16x8*)(WT + (long)o * K + k);
      acc[nf] = mfma16(av, as_bf16x8(braw), acc[nf]);
    }
  }
}

__global__ __launch_bounds__(256) void k_gemm_pair(const float* __restrict__ img,
    const float* __restrict__ loc, const u16* __restrict__ W11T,
    const float* __restrict__ b11, float* __restrict__ h11,
    const u16* __restrict__ W21T, const float* __restrict__ b21,
    float* __restrict__ h21) {
  const int t = threadIdx.x;
  const int wid = t >> 6, lane = t & 63;
  const int l15 = lane & 15, lhi = lane >> 4;
  const int b0 = blockIdx.x * 16;
  const int o0 = wid * 64;
  const long row = b0 + l15;
  const u16* WT = (blockIdx.y == 0) ? W11T : W21T;
  const float* bias = (blockIdx.y == 0) ? b11 : b21;
  float* out = (blockIdx.y == 0) ? h11 : h21;
  f32x4 acc[4] = {};
  gemm_small_core(img, loc, 512, WT, acc, o0, row);
#pragma unroll
  for (int nf = 0; nf < 4; ++nf) {
    int o = o0 + nf * 16 + l15;
    float bs = bias[o];
#pragma unroll
    for (int r = 0; r < 4; ++r) {
      long b = b0 + lhi * 4 + r;
      out[b * 256 + o] = fmaxf(acc[nf][r] + bs, 0.f);
    }
  }
}

// wgt12B = bf16(h11 @ w12 + b12)
__global__ __launch_bounds__(256) void k_gemm_wgt12(const float* __restrict__ h11,
    const u16* __restrict__ W12T, const float* __restrict__ b12,
    u16* __restrict__ wgt12B) {
  const int t = threadIdx.x;
  const int wid = t >> 6, lane = t & 63;
  const int l15 = lane & 15, lhi = lane >> 4;
  const int b0 = blockIdx.x * 16;
  const int o0 = wid * 64;
  const long row = b0 + l15;
  f32x4 acc[4] = {};
  gemm_small_core(h11, nullptr, 256, W12T, acc, o0, row);
#pragma unroll
  for (int nf = 0; nf < 4; ++nf) {
    int o = o0 + nf * 16 + l15;
    float bs = b12[o];
#pragma unroll
    for (int r = 0; r < 4; ++r) {
      long b = b0 + lhi * 4 + r;
      wgt12B[b * 256 + o] = f2bf(acc[nf][r] + bs);
    }
  }
}

// ---------------------------------------------------------------------------
// Big GEMM v5: partials[chunk][o][b] = sum_p W2T[o][p] * M[b][p]
//   M[b][p=k*256+i] = h21[b][k]*wgt12[b][i] (k<256), = wgt12[b][i] (bias rows)
// Scale-deferred: per kk-block (256 p), sub += W2T x bf16(wgt12); then
// acc[col b] += h21[b][kk] * sub. wgt12-bf16 tile static in LDS (64KB,
// XOR-swizzled); A fragments direct-from-global, ping-pong reg prefetch.
// NO barriers / ds_writes / cvt in the main loop.
// tile [256 o][128 b], 8 waves (4 og x 2 bg), per-wave [64][64], split-K 8.
// grid 256 linear; chunk = bid&7 (XCD-pins each chunk's 4MB A-slice in L2).
// ---------------------------------------------------------------------------
__global__ __launch_bounds__(512, 2) void k_big(const u16* __restrict__ W2T,
    const float* __restrict__ h21, const u16* __restrict__ wgt12B,
    float* __restrict__ partials) {
  __shared__ u16 ldsW[128 * 256];   // 64KB, [b-row][slot swizzled low-3]
  const int t = threadIdx.x;
  const int wid = t >> 6, lane = t & 63;
  const int l15 = lane & 15, lhi = lane >> 4;
  const int n = blockIdx.x;
  const int chunk = n & 7;
  const int b0 = (n >> 3) * 128;
  const int og = wid >> 1, bg = wid & 1;
  const int nblk = (chunk == 7) ? 33 : 32;

  // ---- stage wgt12B tile [128][256] once, swizzled
  {
    const int r = t >> 2, q = t & 3;
    const u16* src = wgt12B + (long)(b0 + r) * 256 + q * 64;
#pragma unroll
    for (int j = 0; j < 8; ++j) {
      u16x8 v = *(const u16x8*)(src + j * 8);
      const int slot = q * 8 + j;
      const int sw = (slot & 24) | (j ^ (r & 7));
      *(u16x8*)&ldsW[r * 256 + sw * 8] = v;
    }
  }

  // A global bases (per mf); p advances 256 elems (512B) per kk-block
  const u16* aB[4];
#pragma unroll
  for (int mf = 0; mf < 4; ++mf)
    aB[mf] = W2T + (long)(og * 64 + mf * 16 + l15) * 65792 + chunk * 8192 + lhi * 8;

  // LDS fragment bases per (nf, ksub); +stp*128B immediate per step
  const u16* lB[4][2];
  {
    const int g0 = lhi ^ (l15 & 7);
#pragma unroll
    for (int nf = 0; nf < 4; ++nf) {
      const int row = bg * 64 + nf * 16 + l15;
      lB[nf][0] = ldsW + row * 256 + g0 * 8;
      lB[nf][1] = ldsW + row * 256 + (g0 ^ 4) * 8;
    }
  }
  const long hrow = (long)(b0 + bg * 64 + l15) * 256;

  f32x4 acc[4][4] = {};
  u16x8 A0[4][2], A1[4][2];

  auto PREF = [&](u16x8 (&S)[4][2], int byteOff) {
#pragma unroll
    for (int mf = 0; mf < 4; ++mf)
#pragma unroll
      for (int ks = 0; ks < 2; ++ks)
        S[mf][ks] = *(const u16x8*)((const char*)aB[mf] + byteOff + ks * 64);
  };
  auto STEP = [&](const u16x8 (&S)[4][2], f32x4 (&sub)[4][4], int stp) {
#pragma unroll
    for (int ks = 0; ks < 2; ++ks) {
      bf16x8 bv[4];
#pragma unroll
      for (int nf = 0; nf < 4; ++nf)
        bv[nf] = as_bf16x8(*(const u16x8*)((const char*)lB[nf][ks] + stp * 128));
#pragma unroll
      for (int mf = 0; mf < 4; ++mf)
#pragma unroll
        for (int nf = 0; nf < 4; ++nf)
          sub[mf][nf] = mfma16(as_bf16x8(S[mf][ks]), bv[nf], sub[mf][nf]);
    }
  };

  __syncthreads();                 // wgt tile ready (only barrier)
  PREF(A0, 0);

  for (int kb = 0; kb < nblk; ++kb) {
    const int kkg = chunk * 32 + kb;       // 256 => bias block (scale 1)
    float sc[4];
#pragma unroll
    for (int nf = 0; nf < 4; ++nf)
      sc[nf] = (kkg < 256) ? h21[hrow + (long)nf * 4096 + kkg] : 1.0f;
    f32x4 sub[4][4] = {};
    PREF(A1, 128);  STEP(A0, sub, 0);
    PREF(A0, 256);  STEP(A1, sub, 1);
    PREF(A1, 384);  STEP(A0, sub, 2);
    PREF(A0, 512);  STEP(A1, sub, 3);
#pragma unroll
    for (int mf = 0; mf < 4; ++mf)
      aB[mf] = (const u16*)((const char*)aB[mf] + 512);
#pragma unroll
    for (int mf = 0; mf < 4; ++mf)
#pragma unroll
      for (int nf = 0; nf < 4; ++nf)
        acc[mf][nf] += sc[nf] * sub[mf][nf];
  }

  const long cb = (long)chunk * (256L * 4096);
#pragma unroll
  for (int mf = 0; mf < 4; ++mf)
#pragma unroll
    for (int nf = 0; nf < 4; ++nf)
#pragma unroll
      for (int r = 0; r < 4; ++r) {
        const int o = og * 64 + mf * 16 + lhi * 4 + r;
        const int bgl = b0 + bg * 64 + nf * 16 + l15;
        partials[cb + (long)o * 4096 + bgl] = acc[mf][nf][r];
      }
}

// ---------------------------------------------------------------------------
// Fused tail: reduce split-K partials + LN + ReLU -> bf16 LDS tile ->
// MFMA GEMM with w3 + LN + ReLU -> out. grid 256, block 256 (16 b-rows).
// ---------------------------------------------------------------------------
__global__ __launch_bounds__(256) void k_tail(const float* __restrict__ parts,
    const float* __restrict__ lng, const float* __restrict__ lnb,
    const u16* __restrict__ W3T, const float* __restrict__ g3,
    const float* __restrict__ bb3, float* __restrict__ out) {
  __shared__ float tile[16][260];
  __shared__ u16 A16[16][264];
  __shared__ float s1s[4][16], s2s[4][16];
  __shared__ float mz[16], rz[16];
  const int t = threadIdx.x;
  const int b0 = blockIdx.x * 16;
  {
    const int oq = t >> 2, bseg = t & 3;
#pragma unroll
    for (int j = 0; j < 4; ++j) {
      const int o = oq + j * 64;
      f32x4 s = {};
#pragma unroll
      for (int c = 0; c < 8; ++c)
        s += *(const f32x4*)&parts[(long)c * (256L * 4096) + (long)o * 4096 + b0 + bseg * 4];
#pragma unroll
      for (int q = 0; q < 4; ++q) tile[bseg * 4 + q][o] = s[q];
    }
  }
  __syncthreads();
  {
    const int r = t >> 4, og = t & 15;
    float v[16];
    float s1 = 0.f, s2 = 0.f;
#pragma unroll
    for (int q = 0; q < 16; ++q) {
      float x = tile[r][og * 16 + q];
      v[q] = x; s1 += x; s2 += x * x;
    }
    s1 += __shfl_xor(s1, 1); s2 += __shfl_xor(s2, 1);
    s1 += __shfl_xor(s1, 2); s2 += __shfl_xor(s2, 2);
    s1 += __shfl_xor(s1, 4); s2 += __shfl_xor(s2, 4);
    s1 += __shfl_xor(s1, 8); s2 += __shfl_xor(s2, 8);
    float mean = s1 * (1.f / 256.f);
    float var = s2 * (1.f / 256.f) - mean * mean;
    float rstd = rsqrtf(var + 1e-5f);
    u16x8 w0, w1;
#pragma unroll
    for (int q = 0; q < 16; ++q) {
      int o = og * 16 + q;
      float x = (v[q] - mean) * rstd * lng[o] + lnb[o];
      x = fmaxf(x, 0.f);
      if (q < 8) w0[q] = f2bf(x); else w1[q - 8] = f2bf(x);
    }
    *(u16x8*)&A16[r][og * 16] = w0;
    *(u16x8*)&A16[r][og * 16 + 8] = w1;
  }
  __syncthreads();
  const int wid = t >> 6, lane = t & 63;
  const int l15 = lane & 15, lhi = lane >> 4;
  const int wo = wid * 64;
  f32x4 acc[4] = {};
  for (int ks = 0; ks < 256; ks += 32) {
    const int k = ks + lhi * 8;
    bf16x8 av = as_bf16x8(*(const u16x8*)&A16[l15][k]);
#pragma unroll
    for (int nf = 0; nf < 4; ++nf) {
      int o = wo + nf * 16 + l15;
      u16x8 braw = *(const u16x8*)(W3T + (long)o * 256 + k);
      acc[nf] = mfma16(av, as_bf16x8(braw), acc[nf]);
    }
  }
#pragma unroll
  for (int r = 0; r < 4; ++r) {
    float s1 = 0.f, s2 = 0.f;
#pragma unroll
    for (int nf = 0; nf < 4; ++nf) { float x = acc[nf][r]; s1 += x; s2 += x * x; }
    s1 += __shfl_xor(s1, 1); s2 += __shfl_xor(s2, 1);
    s1 += __shfl_xor(s1, 2); s2 += __shfl_xor(s2, 2);
    s1 += __shfl_xor(s1, 4); s2 += __shfl_xor(s2, 4);
    s1 += __shfl_xor(s1, 8); s2 += __shfl_xor(s2, 8);
    if (l15 == 0) { s1s[wid][lhi * 4 + r] = s1; s2s[wid][lhi * 4 + r] = s2; }
  }
  __syncthreads();
  if (t < 16) {
    float s1 = s1s[0][t] + s1s[1][t] + s1s[2][t] + s1s[3][t];
    float s2 = s2s[0][t] + s2s[1][t] + s2s[2][t] + s2s[3][t];
    float mean = s1 * (1.f / 256.f);
    float var = s2 * (1.f / 256.f) - mean * mean;
    mz[t] = mean; rz[t] = rsqrtf(var + 1e-5f);
  }
  __syncthreads();
#pragma unroll
  for (int r = 0; r < 4; ++r) {
    const int b = lhi * 4 + r;
    const float mean = mz[b], rstd = rz[b];
#pragma unroll
    for (int nf = 0; nf < 4; ++nf) {
      int o = wo + nf * 16 + l15;
      float x = (acc[nf][r] - mean) * rstd * g3[o] + bb3[o];
      out[(long)(b0 + b) * 256 + o] = fmaxf(x, 0.f);
    }
  }
}

// ---------------------------------------------------------------------------
extern "C" void kernel_launch(void* const* d_in, const int* in_sizes, int n_in,
                              void* d_out, int out_size, void* d_ws, size_t ws_size,
                              hipStream_t stream) {
  const float* img = (const float*)d_in[0];
  const float* loc = (const float*)d_in[1];
  const float* w11 = (const float*)d_in[2];
  const float* b11 = (const float*)d_in[3];
  const float* w12 = (const float*)d_in[4];
  const float* b12 = (const float*)d_in[5];
  const float* w21 = (const float*)d_in[6];
  const float* b21 = (const float*)d_in[7];
  const float* w22 = (const float*)d_in[8];
  const float* b22 = (const float*)d_in[9];
  const float* lng = (const float*)d_in[10];
  const float* lnb = (const float*)d_in[11];
  const float* w3  = (const float*)d_in[12];
  const float* g3  = (const float*)d_in[13];
  const float* bb3 = (const float*)d_in[14];

  char* ws = (char*)d_ws;
  u16* W2T    = (u16*)(ws);                     // 33,685,504
  u16* W11T   = (u16*)(ws + 33685504);          // 262,144
  u16* W21T   = (u16*)(ws + 33947648);          // 262,144
  u16* W12T   = (u16*)(ws + 34209792);          // 131,072
  u16* W3T    = (u16*)(ws + 34340864);          // 131,072
  float* h11  = (float*)(ws + 34471936);        // 4,194,304
  float* h21  = (float*)(ws + 38666240);        // 4,194,304
  u16* wgt12B = (u16*)(ws + 42860544);          // 2,097,152
  float* parts = (float*)(ws + 47054848);       // 33,554,432 (end 80,609,280)
  float* outp  = (float*)d_out;

  // passthrough output (independent) first
  hipMemcpyAsync(outp + 1048576, loc, 4194304, hipMemcpyDeviceToDevice, stream);

  // weight transposes (fp32 -> bf16)
  hipLaunchKernelGGL(k_transpose, dim3(1024, 4), dim3(256), 0, stream,
                     w22, W2T, (long)65792, (long)0);
  hipLaunchKernelGGL(k_transpose_multi, dim3(28, 4), dim3(256), 0, stream,
                     b22, w11, w21, w12, w3, W2T, W11T, W21T, W12T, W3T);

  // h11 = relu(cat@w11+b11), h21 = relu(cat@w21+b21)
  hipLaunchKernelGGL(k_gemm_pair, dim3(256, 2), dim3(256), 0, stream,
                     img, loc, W11T, b11, h11, W21T, b21, h21);
  // wgt12B = bf16(h11@w12+b12)
  hipLaunchKernelGGL(k_gemm_wgt12, dim3(256), dim3(256), 0, stream,
                     h11, W12T, b12, wgt12B);

  // big fused hypernet GEMM (split-K partials), barrier-free main loop
  hipLaunchKernelGGL(k_big, dim3(256), dim3(512), 0, stream,
                     W2T, h21, wgt12B, parts);

  // fused reduce+LN+ReLU + final GEMM+LN+ReLU
  hipLaunchKernelGGL(k_tail, dim3(256), dim3(256), 0, stream,
                     parts, lng, lnb, W3T, g3, bb3, outp);
}

// Round 6
// 308.703 us; speedup vs baseline: 1.7652x; 1.7652x over previous
//
#include <hip/hip_runtime.h>
#include <stdint.h>

typedef unsigned short u16;
typedef __bf16 bf16;
typedef bf16 bf16x8 __attribute__((ext_vector_type(8)));
typedef u16 u16x8 __attribute__((ext_vector_type(8)));
typedef float f32x4 __attribute__((ext_vector_type(4)));

__device__ __forceinline__ u16 f2bf(float f) {
  union { float f; unsigned u; } v; v.f = f;
  unsigned u = v.u;
  u += 0x7FFFu + ((u >> 16) & 1u);   // RNE
  return (u16)(u >> 16);
}

__device__ __forceinline__ bf16x8 as_bf16x8(u16x8 v) {
  return __builtin_bit_cast(bf16x8, v);
}

__device__ __forceinline__ f32x4 mfma16(bf16x8 a, bf16x8 b, f32x4 c) {
  return __builtin_amdgcn_mfma_f32_16x16x32_bf16(a, b, c, 0, 0, 0);
}

// ---------------------------------------------------------------------------
// w22 transpose + cvt: src [R][256] f32 -> dst[o][r] bf16  (16B stores)
// ---------------------------------------------------------------------------
__global__ __launch_bounds__(256) void k_transpose(const float* __restrict__ src,
    u16* __restrict__ dst, long dstStride, long dstOff) {
  __shared__ float tile[64][65];
  const int t = threadIdx.x;
  const int tr = t >> 6, tc = t & 63;
  const long rb = (long)blockIdx.x * 64;
  const int ob = blockIdx.y * 64;
#pragma unroll
  for (int i = 0; i < 16; ++i) {
    int r = i * 4 + tr;
    tile[r][tc] = src[(rb + r) * 256 + ob + tc];
  }
  __syncthreads();
  const int orow = t >> 2, seg = t & 3;
#pragma unroll
  for (int h = 0; h < 2; ++h) {
    u16x8 v;
#pragma unroll
    for (int j = 0; j < 8; ++j) v[j] = f2bf(tile[seg * 16 + h * 8 + j][orow]);
    *(u16x8*)&dst[(long)(ob + orow) * dstStride + dstOff + rb + seg * 16 + h * 8] = v;
  }
}

// ---------------------------------------------------------------------------
// 5 small transposes merged: grid (28, 4)
// ---------------------------------------------------------------------------
__global__ __launch_bounds__(256) void k_transpose_multi(
    const float* __restrict__ b22, const float* __restrict__ w11,
    const float* __restrict__ w21, const float* __restrict__ w12,
    const float* __restrict__ w3, u16* __restrict__ W2T, u16* __restrict__ W11T,
    u16* __restrict__ W21T, u16* __restrict__ W12T, u16* __restrict__ W3T) {
  __shared__ float tile[64][65];
  const int x = blockIdx.x;
  const float* src; u16* dst; long stride, off; int rb;
  if (x < 4)       { src = b22; dst = W2T;  stride = 65792; off = 65536; rb = x; }
  else if (x < 12) { src = w11; dst = W11T; stride = 512;   off = 0;     rb = x - 4; }
  else if (x < 20) { src = w21; dst = W21T; stride = 512;   off = 0;     rb = x - 12; }
  else if (x < 24) { src = w12; dst = W12T; stride = 256;   off = 0;     rb = x - 20; }
  else             { src = w3;  dst = W3T;  stride = 256;   off = 0;     rb = x - 24; }
  const long rbase = (long)rb * 64;
  const int t = threadIdx.x;
  const int tr = t >> 6, tc = t & 63;
  const int ob = blockIdx.y * 64;
#pragma unroll
  for (int i = 0; i < 16; ++i) {
    int r = i * 4 + tr;
    tile[r][tc] = src[(rbase + r) * 256 + ob + tc];
  }
  __syncthreads();
  const int orow = t >> 2, seg = t & 3;
#pragma unroll
  for (int h = 0; h < 2; ++h) {
    u16x8 v;
#pragma unroll
    for (int j = 0; j < 8; ++j) v[j] = f2bf(tile[seg * 16 + h * 8 + j][orow]);
    *(u16x8*)&dst[(long)(ob + orow) * stride + off + rbase + seg * 16 + h * 8] = v;
  }
}

// ---------------------------------------------------------------------------
// Small MFMA GEMM: h = relu(cat @ W^T + bias), f32 out. grid (256, 2).
// ---------------------------------------------------------------------------
__device__ __forceinline__ void gemm_small_core(const float* A0, const float* A1,
    int K, const u16* WT, f32x4 (&acc)[4], int o0, long row) {
  const int lane = threadIdx.x & 63;
  const int l15 = lane & 15, lhi = lane >> 4;
  const int kg = lhi * 8;
  for (int ks = 0; ks < K; ks += 32) {
    int k = ks + kg;
    const float* ap = (A1 != nullptr && k >= 256) ? (A1 + row * 256 + (k - 256))
                                                  : (A0 + row * 256 + k);
    f32x4 f0 = *(const f32x4*)ap;
    f32x4 f1 = *(const f32x4*)(ap + 4);
    u16x8 a;
    a[0]=f2bf(f0[0]); a[1]=f2bf(f0[1]); a[2]=f2bf(f0[2]); a[3]=f2bf(f0[3]);
    a[4]=f2bf(f1[0]); a[5]=f2bf(f1[1]); a[6]=f2bf(f1[2]); a[7]=f2bf(f1[3]);
    bf16x8 av = as_bf16x8(a);
#pragma unroll
    for (int nf = 0; nf < 4; ++nf) {
      int o = o0 + nf * 16 + l15;
      u16x8 braw = *(const u16x8*)(WT + (long)o * K + k);
      acc[nf] = mfma16(av, as_bf16x8(braw), acc[nf]);
    }
  }
}

__global__ __launch_bounds__(256) void k_gemm_pair(const float* __restrict__ img,
    const float* __restrict__ loc, const u16* __restrict__ W11T,
    const float* __restrict__ b11, float* __restrict__ h11,
    const u16* __restrict__ W21T, const float* __restrict__ b21,
    float* __restrict__ h21) {
  const int t = threadIdx.x;
  const int wid = t >> 6, lane = t & 63;
  const int l15 = lane & 15, lhi = lane >> 4;
  const int b0 = blockIdx.x * 16;
  const int o0 = wid * 64;
  const long row = b0 + l15;
  const u16* WT = (blockIdx.y == 0) ? W11T : W21T;
  const float* bias = (blockIdx.y == 0) ? b11 : b21;
  float* out = (blockIdx.y == 0) ? h11 : h21;
  f32x4 acc[4] = {};
  gemm_small_core(img, loc, 512, WT, acc, o0, row);
#pragma unroll
  for (int nf = 0; nf < 4; ++nf) {
    int o = o0 + nf * 16 + l15;
    float bs = bias[o];
#pragma unroll
    for (int r = 0; r < 4; ++r) {
      long b = b0 + lhi * 4 + r;
      out[b * 256 + o] = fmaxf(acc[nf][r] + bs, 0.f);
    }
  }
}

// wgt12B = bf16(h11 @ w12 + b12)
__global__ __launch_bounds__(256) void k_gemm_wgt12(const float* __restrict__ h11,
    const u16* __restrict__ W12T, const float* __restrict__ b12,
    u16* __restrict__ wgt12B) {
  const int t = threadIdx.x;
  const int wid = t >> 6, lane = t & 63;
  const int l15 = lane & 15, lhi = lane >> 4;
  const int b0 = blockIdx.x * 16;
  const int o0 = wid * 64;
  const long row = b0 + l15;
  f32x4 acc[4] = {};
  gemm_small_core(h11, nullptr, 256, W12T, acc, o0, row);
#pragma unroll
  for (int nf = 0; nf < 4; ++nf) {
    int o = o0 + nf * 16 + l15;
    float bs = b12[o];
#pragma unroll
    for (int r = 0; r < 4; ++r) {
      long b = b0 + lhi * 4 + r;
      wgt12B[b * 256 + o] = f2bf(acc[nf][r] + bs);
    }
  }
}

// ---------------------------------------------------------------------------
// Big GEMM v6: partials[chunk][o][b] = sum_p W2T[o][p] * M[b][p]
//   M[b][p=k*256+i] = h21[b][k]*wgt12[b][i] (k<256), = wgt12[b][i] (bias rows)
// Deferred scale (r5 algebra) + LDS-staged operands (r3 structure):
//  - ldsW: static wgt12B tile [128b][256i] bf16, 64KB, staged once, swizzled
//  - ldsA: per-step A tile [128o][64p], 16KB, reg-prefetch + ds_write,
//    2 barriers/step (r3-proven)
//  - per kk-block (4 steps): sub += A x wgt12B; then acc += h21[b][kk]*sub
// block 256 thr (4 waves, 2og x 2bg), wave tile [64o][64b], split-K 8.
// grid 512: chunk = n&7 (XCD L2 pinning), o-half, b-tile.
// ---------------------------------------------------------------------------
__global__ __launch_bounds__(256, 2) void k_big(const u16* __restrict__ W2T,
    const float* __restrict__ h21, const u16* __restrict__ wgt12B,
    float* __restrict__ partials) {
  __shared__ u16 ldsW[128 * 256];   // 64KB
  __shared__ u16 ldsA[128 * 64];    // 16KB
  const int t = threadIdx.x;
  const int wid = t >> 6, lane = t & 63;
  const int l15 = lane & 15, lhi = lane >> 4;
  const int n = blockIdx.x;
  const int chunk = n & 7;
  const int q = n >> 3;
  const int o_base = (q & 1) * 128;
  const int b0 = (q >> 1) * 128;
  const int og = wid >> 1, bg = wid & 1;
  const int nkb = (chunk == 7) ? 33 : 32;
  const int NS = nkb * 4;

  // ---- stage wgt12B tile [128][256] once (swizzled low-3 of slot-group)
  {
    const int r = t >> 1, h = t & 1;
    const u16* src = wgt12B + (long)(b0 + r) * 256 + h * 128;
#pragma unroll
    for (int m = 0; m < 16; ++m) {
      u16x8 v = *(const u16x8*)(src + m * 8);
      const int sg = h * 16 + m;
      const int sw = (sg & 24) | ((sg & 7) ^ (r & 7));
      *(u16x8*)&ldsW[r * 256 + sw * 8] = v;
    }
  }

  // A staging ids: thread covers row ar, 64B (4 x 16B slot-groups)
  const int ar = t >> 1;
  const int ah = t & 1;
  const u16* agbase = W2T + (long)(o_base + ar) * 65792 + chunk * 8192 + ah * 32;
  u16* awbase = ldsA + ar * 64;

  f32x4 acc[4][4] = {};
  u16x8 sa[4];

  auto LOADA = [&](int s) {
    const u16* p = agbase + (long)s * 64;
#pragma unroll
    for (int j = 0; j < 4; ++j) sa[j] = *(const u16x8*)(p + j * 8);
  };
  auto WRITEA = [&]() {
#pragma unroll
    for (int j = 0; j < 4; ++j) {
      const int sg = ah * 4 + j;
      *(u16x8*)&awbase[(sg ^ (ar & 7)) * 8] = sa[j];
    }
  };

  LOADA(0);
  int s = 0;
  for (int kb = 0; kb < nkb; ++kb) {
    const int kk = chunk * 32 + kb;
    float sc[4];
#pragma unroll
    for (int nf = 0; nf < 4; ++nf)
      sc[nf] = (kk < 256)
                 ? h21[(long)(b0 + bg * 64 + nf * 16 + l15) * 256 + kk]
                 : 1.0f;
    f32x4 sub[4][4] = {};
#pragma unroll
    for (int s4 = 0; s4 < 4; ++s4) {
      __syncthreads();               // prior step's reads done
      WRITEA();
      __syncthreads();               // A tile ready
      if (s + 1 < NS) LOADA(s + 1);  // prefetch under compute
#pragma unroll
      for (int ksub = 0; ksub < 2; ++ksub) {
        const int x = ksub * 4 + lhi;
        bf16x8 af[4], bv[4];
#pragma unroll
        for (int mf = 0; mf < 4; ++mf) {
          const int ro = og * 64 + mf * 16 + l15;
          af[mf] = as_bf16x8(*(const u16x8*)&ldsA[ro * 64 + ((x ^ (ro & 7)) * 8)]);
        }
#pragma unroll
        for (int nf = 0; nf < 4; ++nf) {
          const int rw = bg * 64 + nf * 16 + l15;
          bv[nf] = as_bf16x8(
              *(const u16x8*)&ldsW[rw * 256 + (s4 * 8 + (x ^ (rw & 7))) * 8]);
        }
        __builtin_amdgcn_s_setprio(1);
#pragma unroll
        for (int mf = 0; mf < 4; ++mf)
#pragma unroll
          for (int nf = 0; nf < 4; ++nf)
            sub[mf][nf] = mfma16(af[mf], bv[nf], sub[mf][nf]);
        __builtin_amdgcn_s_setprio(0);
      }
      ++s;
    }
#pragma unroll
    for (int mf = 0; mf < 4; ++mf)
#pragma unroll
      for (int nf = 0; nf < 4; ++nf)
        acc[mf][nf] += sc[nf] * sub[mf][nf];
  }

  const long cb = (long)chunk * (256L * 4096);
#pragma unroll
  for (int mf = 0; mf < 4; ++mf)
#pragma unroll
    for (int nf = 0; nf < 4; ++nf)
#pragma unroll
      for (int r = 0; r < 4; ++r) {
        const int o = o_base + og * 64 + mf * 16 + lhi * 4 + r;
        const int bgl = b0 + bg * 64 + nf * 16 + l15;
        partials[cb + (long)o * 4096 + bgl] = acc[mf][nf][r];
      }
}

// ---------------------------------------------------------------------------
// Fused tail: reduce split-K partials + LN + ReLU -> bf16 LDS tile ->
// MFMA GEMM with w3 + LN + ReLU -> out. grid 256, block 256 (16 b-rows).
// ---------------------------------------------------------------------------
__global__ __launch_bounds__(256) void k_tail(const float* __restrict__ parts,
    const float* __restrict__ lng, const float* __restrict__ lnb,
    const u16* __restrict__ W3T, const float* __restrict__ g3,
    const float* __restrict__ bb3, float* __restrict__ out) {
  __shared__ float tile[16][260];
  __shared__ u16 A16[16][264];
  __shared__ float s1s[4][16], s2s[4][16];
  __shared__ float mz[16], rz[16];
  const int t = threadIdx.x;
  const int b0 = blockIdx.x * 16;
  {
    const int oq = t >> 2, bseg = t & 3;
#pragma unroll
    for (int j = 0; j < 4; ++j) {
      const int o = oq + j * 64;
      f32x4 s = {};
#pragma unroll
      for (int c = 0; c < 8; ++c)
        s += *(const f32x4*)&parts[(long)c * (256L * 4096) + (long)o * 4096 + b0 + bseg * 4];
#pragma unroll
      for (int q = 0; q < 4; ++q) tile[bseg * 4 + q][o] = s[q];
    }
  }
  __syncthreads();
  {
    const int r = t >> 4, og = t & 15;
    float v[16];
    float s1 = 0.f, s2 = 0.f;
#pragma unroll
    for (int q = 0; q < 16; ++q) {
      float x = tile[r][og * 16 + q];
      v[q] = x; s1 += x; s2 += x * x;
    }
    s1 += __shfl_xor(s1, 1); s2 += __shfl_xor(s2, 1);
    s1 += __shfl_xor(s1, 2); s2 += __shfl_xor(s2, 2);
    s1 += __shfl_xor(s1, 4); s2 += __shfl_xor(s2, 4);
    s1 += __shfl_xor(s1, 8); s2 += __shfl_xor(s2, 8);
    float mean = s1 * (1.f / 256.f);
    float var = s2 * (1.f / 256.f) - mean * mean;
    float rstd = rsqrtf(var + 1e-5f);
    u16x8 w0, w1;
#pragma unroll
    for (int q = 0; q < 16; ++q) {
      int o = og * 16 + q;
      float x = (v[q] - mean) * rstd * lng[o] + lnb[o];
      x = fmaxf(x, 0.f);
      if (q < 8) w0[q] = f2bf(x); else w1[q - 8] = f2bf(x);
    }
    *(u16x8*)&A16[r][og * 16] = w0;
    *(u16x8*)&A16[r][og * 16 + 8] = w1;
  }
  __syncthreads();
  const int wid = t >> 6, lane = t & 63;
  const int l15 = lane & 15, lhi = lane >> 4;
  const int wo = wid * 64;
  f32x4 acc[4] = {};
  for (int ks = 0; ks < 256; ks += 32) {
    const int k = ks + lhi * 8;
    bf16x8 av = as_bf16x8(*(const u16x8*)&A16[l15][k]);
#pragma unroll
    for (int nf = 0; nf < 4; ++nf) {
      int o = wo + nf * 16 + l15;
      u16x8 braw = *(const u16x8*)(W3T + (long)o * 256 + k);
      acc[nf] = mfma16(av, as_bf16x8(braw), acc[nf]);
    }
  }
#pragma unroll
  for (int r = 0; r < 4; ++r) {
    float s1 = 0.f, s2 = 0.f;
#pragma unroll
    for (int nf = 0; nf < 4; ++nf) { float x = acc[nf][r]; s1 += x; s2 += x * x; }
    s1 += __shfl_xor(s1, 1); s2 += __shfl_xor(s2, 1);
    s1 += __shfl_xor(s1, 2); s2 += __shfl_xor(s2, 2);
    s1 += __shfl_xor(s1, 4); s2 += __shfl_xor(s2, 4);
    s1 += __shfl_xor(s1, 8); s2 += __shfl_xor(s2, 8);
    if (l15 == 0) { s1s[wid][lhi * 4 + r] = s1; s2s[wid][lhi * 4 + r] = s2; }
  }
  __syncthreads();
  if (t < 16) {
    float s1 = s1s[0][t] + s1s[1][t] + s1s[2][t] + s1s[3][t];
    float s2 = s2s[0][t] + s2s[1][t] + s2s[2][t] + s2s[3][t];
    float mean = s1 * (1.f / 256.f);
    float var = s2 * (1.f / 256.f) - mean * mean;
    mz[t] = mean; rz[t] = rsqrtf(var + 1e-5f);
  }
  __syncthreads();
#pragma unroll
  for (int r = 0; r < 4; ++r) {
    const int b = lhi * 4 + r;
    const float mean = mz[b], rstd = rz[b];
#pragma unroll
    for (int nf = 0; nf < 4; ++nf) {
      int o = wo + nf * 16 + l15;
      float x = (acc[nf][r] - mean) * rstd * g3[o] + bb3[o];
      out[(long)(b0 + b) * 256 + o] = fmaxf(x, 0.f);
    }
  }
}

// ---------------------------------------------------------------------------
extern "C" void kernel_launch(void* const* d_in, const int* in_sizes, int n_in,
                              void* d_out, int out_size, void* d_ws, size_t ws_size,
                              hipStream_t stream) {
  const float* img = (const float*)d_in[0];
  const float* loc = (const float*)d_in[1];
  const float* w11 = (const float*)d_in[2];
  const float* b11 = (const float*)d_in[3];
  const float* w12 = (const float*)d_in[4];
  const float* b12 = (const float*)d_in[5];
  const float* w21 = (const float*)d_in[6];
  const float* b21 = (const float*)d_in[7];
  const float* w22 = (const float*)d_in[8];
  const float* b22 = (const float*)d_in[9];
  const float* lng = (const float*)d_in[10];
  const float* lnb = (const float*)d_in[11];
  const float* w3  = (const float*)d_in[12];
  const float* g3  = (const float*)d_in[13];
  const float* bb3 = (const float*)d_in[14];

  char* ws = (char*)d_ws;
  u16* W2T    = (u16*)(ws);                     // 33,685,504
  u16* W11T   = (u16*)(ws + 33685504);          // 262,144
  u16* W21T   = (u16*)(ws + 33947648);          // 262,144
  u16* W12T   = (u16*)(ws + 34209792);          // 131,072
  u16* W3T    = (u16*)(ws + 34340864);          // 131,072
  float* h11  = (float*)(ws + 34471936);        // 4,194,304
  float* h21  = (float*)(ws + 38666240);        // 4,194,304
  u16* wgt12B = (u16*)(ws + 42860544);          // 2,097,152
  float* parts = (float*)(ws + 47054848);       // 33,554,432 (end 80,609,280)
  float* outp  = (float*)d_out;

  // passthrough output (independent) first
  hipMemcpyAsync(outp + 1048576, loc, 4194304, hipMemcpyDeviceToDevice, stream);

  // weight transposes (fp32 -> bf16)
  hipLaunchKernelGGL(k_transpose, dim3(1024, 4), dim3(256), 0, stream,
                     w22, W2T, (long)65792, (long)0);
  hipLaunchKernelGGL(k_transpose_multi, dim3(28, 4), dim3(256), 0, stream,
                     b22, w11, w21, w12, w3, W2T, W11T, W21T, W12T, W3T);

  // h11 = relu(cat@w11+b11), h21 = relu(cat@w21+b21)
  hipLaunchKernelGGL(k_gemm_pair, dim3(256, 2), dim3(256), 0, stream,
                     img, loc, W11T, b11, h11, W21T, b21, h21);
  // wgt12B = bf16(h11@w12+b12)
  hipLaunchKernelGGL(k_gemm_wgt12, dim3(256), dim3(256), 0, stream,
                     h11, W12T, b12, wgt12B);

  // big fused hypernet GEMM (split-K partials)
  hipLaunchKernelGGL(k_big, dim3(512), dim3(256), 0, stream,
                     W2T, h21, wgt12B, parts);

  // fused reduce+LN+ReLU + final GEMM+LN+ReLU
  hipLaunchKernelGGL(k_tail, dim3(256), dim3(256), 0, stream,
                     parts, lng, lnb, W3T, g3, bb3, outp);
}